// Round 1
// baseline (416.492 us; speedup 1.0000x reference)
//
#include <hip/hip_runtime.h>
#include <math.h>

// Shapes (compile-time): B=8, N=256, NID=64, V=128, GH=128, PHI=256, RHO=128
#define NB    8
#define NN    256
#define BNTOT 2048          // B*N
#define DV    128           // V == GH
#define DPHI  256

// ---------------------------------------------------------------------------
// H = relu(X @ emb1_w + emb1_b) @ emb2_w + emb2_b        (one row per block)
// ---------------------------------------------------------------------------
__global__ void k_embed(const float* __restrict__ X,
                        const float* __restrict__ w1, const float* __restrict__ b1,
                        const float* __restrict__ w2, const float* __restrict__ b2,
                        float* __restrict__ H) {
    const int row = blockIdx.x;     // 0..2047
    const int t   = threadIdx.x;    // 0..127
    __shared__ float xs[64];
    __shared__ float h1[128];
    if (t < 64) xs[t] = X[row * 64 + t];
    __syncthreads();
    float acc = b1[t];
    #pragma unroll 8
    for (int k = 0; k < 64; ++k) acc = fmaf(xs[k], w1[k * 128 + t], acc);
    h1[t] = fmaxf(acc, 0.f);
    __syncthreads();
    float acc2 = b2[t];
    #pragma unroll 8
    for (int k = 0; k < 128; ++k) acc2 = fmaf(h1[k], w2[k * 128 + t], acc2);
    H[row * 128 + t] = acc2;
}

// ---------------------------------------------------------------------------
// Per-relation masked column means:
//   mean0[b,j,:] = mean_{i: A[b,i,j]<0} H[b,i,:]   (count clamped to >=1)
//   mean1[b,j,:] = mean_{i: A[b,i,j]>0} H[b,i,:]
// One (b,j) target per block; 128 threads = feature dim.
// ---------------------------------------------------------------------------
__global__ void k_relagg(const float* __restrict__ A, const float* __restrict__ H,
                         float* __restrict__ mean0, float* __restrict__ mean1) {
    const int b = blockIdx.x >> 8;
    const int j = blockIdx.x & 255;
    const int t = threadIdx.x;
    __shared__ float acol[256];
    // A[b, i, j] column (strided load)
    for (int i = t; i < 256; i += 128) acol[i] = A[(size_t)b * 65536 + i * 256 + j];
    __syncthreads();
    float s0 = 0.f, s1 = 0.f;
    float c0 = 0.f, c1 = 0.f;
    const float* Hb = H + (size_t)b * NN * DV;
    for (int i = 0; i < 256; ++i) {
        const float a = acol[i];
        const float h = Hb[i * 128 + t];
        if (a < 0.f)      { s0 += h; c0 += 1.f; }
        else if (a > 0.f) { s1 += h; c1 += 1.f; }
    }
    mean0[(size_t)blockIdx.x * 128 + t] = s0 / fmaxf(c0, 1.f);
    mean1[(size_t)blockIdx.x * 128 + t] = s1 / fmaxf(c1, 1.f);
}

// ---------------------------------------------------------------------------
// H2 = H @ Wroot + bias + mean0 @ Wrel[0] + mean1 @ Wrel[1]
// ---------------------------------------------------------------------------
__global__ void k_lin3(const float* __restrict__ H,
                       const float* __restrict__ mean0, const float* __restrict__ mean1,
                       const float* __restrict__ Wrel,  const float* __restrict__ Wroot,
                       const float* __restrict__ bias,  float* __restrict__ H2) {
    const int row = blockIdx.x;
    const int t   = threadIdx.x;
    __shared__ float hs[128], m0[128], m1[128];
    hs[t] = H[(size_t)row * 128 + t];
    m0[t] = mean0[(size_t)row * 128 + t];
    m1[t] = mean1[(size_t)row * 128 + t];
    __syncthreads();
    const float* W0 = Wrel;
    const float* W1 = Wrel + 128 * 128;
    float acc = bias[t];
    #pragma unroll 4
    for (int k = 0; k < 128; ++k) {
        acc = fmaf(hs[k], Wroot[k * 128 + t], acc);
        acc = fmaf(m0[k], W0[k * 128 + t], acc);
        acc = fmaf(m1[k], W1[k * 128 + t], acc);
    }
    H2[(size_t)row * 128 + t] = acc;
}

// ---------------------------------------------------------------------------
// aggraw[b,i,:] = sum_j |A[b,i,j]| * H2[b,j,:]     (row-contiguous A access)
// ---------------------------------------------------------------------------
__global__ void k_absagg(const float* __restrict__ A, const float* __restrict__ H2,
                         float* __restrict__ aggraw) {
    const int b = blockIdx.x >> 8;
    const int i = blockIdx.x & 255;
    const int t = threadIdx.x;
    __shared__ float arow[256];
    for (int j = t; j < 256; j += 128) arow[j] = fabsf(A[(size_t)b * 65536 + i * 256 + j]);
    __syncthreads();
    float s = 0.f;
    const float* H2b = H2 + (size_t)b * NN * DV;
    for (int j = 0; j < 256; ++j) s = fmaf(arow[j], H2b[j * 128 + t], s);
    aggraw[(size_t)blockIdx.x * 128 + t] = s;
}

// ---------------------------------------------------------------------------
// agg = relu(LN(aggraw)*g+b) -> relu(@law+lab) -> @lbw+lbb   (fused per row)
// ---------------------------------------------------------------------------
__global__ void k_lnmlp(const float* __restrict__ aggraw,
                        const float* __restrict__ g,   const float* __restrict__ bta,
                        const float* __restrict__ law, const float* __restrict__ lab,
                        const float* __restrict__ lbw, const float* __restrict__ lbb,
                        float* __restrict__ agg) {
    const int row = blockIdx.x;
    const int t   = threadIdx.x;   // 0..127
    __shared__ float v[128];
    __shared__ float u[128];
    __shared__ float ssum[2], ssum2[2];
    const float x = aggraw[(size_t)row * 128 + t];
    float s = x, s2 = x * x;
    #pragma unroll
    for (int o = 32; o > 0; o >>= 1) {
        s  += __shfl_down(s,  o, 64);
        s2 += __shfl_down(s2, o, 64);
    }
    const int wave = t >> 6, lane = t & 63;
    if (lane == 0) { ssum[wave] = s; ssum2[wave] = s2; }
    __syncthreads();
    const float mean = (ssum[0] + ssum[1]) * (1.f / 128.f);
    const float var  = (ssum2[0] + ssum2[1]) * (1.f / 128.f) - mean * mean;
    const float inv  = rsqrtf(var + 1e-5f);
    v[t] = fmaxf((x - mean) * inv * g[t] + bta[t], 0.f);
    __syncthreads();
    float a1 = lab[t];
    #pragma unroll 4
    for (int k = 0; k < 128; ++k) a1 = fmaf(v[k], law[k * 128 + t], a1);
    u[t] = fmaxf(a1, 0.f);
    __syncthreads();
    float a2 = lbb[t];
    #pragma unroll 4
    for (int k = 0; k < 128; ++k) a2 = fmaf(u[k], lbw[k * 128 + t], a2);
    agg[(size_t)row * 128 + t] = a2;
}

// ---------------------------------------------------------------------------
// H += agg (elementwise)
// ---------------------------------------------------------------------------
__global__ void k_add(float* __restrict__ H, const float* __restrict__ agg, int n) {
    const int i = blockIdx.x * blockDim.x + threadIdx.x;
    if (i < n) H[i] += agg[i];
}

__global__ void k_zero(float* __restrict__ p, int n) {
    const int i = blockIdx.x * blockDim.x + threadIdx.x;
    if (i < n) p[i] = 0.f;
}

// ---------------------------------------------------------------------------
// DeepSet phi + masked pooling:
//   phi = relu(relu(H@w1+b1)@w2+b2); home_sum[b] += phi*hm; away += phi*(1-hm)
// One row per block, 256 threads (= PHI dim).
// ---------------------------------------------------------------------------
__global__ void k_deepset(const float* __restrict__ H, const float* __restrict__ hm,
                          const float* __restrict__ w1, const float* __restrict__ b1,
                          const float* __restrict__ w2, const float* __restrict__ b2,
                          float* __restrict__ home_sum, float* __restrict__ away_sum) {
    const int row = blockIdx.x;
    const int b   = row >> 8;
    const int t   = threadIdx.x;   // 0..255
    __shared__ float hs[128];
    __shared__ float h[256];
    if (t < 128) hs[t] = H[(size_t)row * 128 + t];
    __syncthreads();
    float acc = b1[t];
    #pragma unroll 4
    for (int k = 0; k < 128; ++k) acc = fmaf(hs[k], w1[k * 256 + t], acc);
    h[t] = fmaxf(acc, 0.f);
    __syncthreads();
    float acc2 = b2[t];
    #pragma unroll 4
    for (int k = 0; k < 256; ++k) acc2 = fmaf(h[k], w2[k * 256 + t], acc2);
    acc2 = fmaxf(acc2, 0.f);
    const float m = hm[row];
    atomicAdd(&home_sum[b * 256 + t], acc2 * m);
    atomicAdd(&away_sum[b * 256 + t], acc2 * (1.f - m));
}

// ---------------------------------------------------------------------------
// out[b] = 0.5 + 0.5*tanh(rho(home)-rho(away));  rho: 256 -> relu(128) -> 1
// One block per batch, 128 threads.
// ---------------------------------------------------------------------------
__global__ void k_rho(const float* __restrict__ home_sum, const float* __restrict__ away_sum,
                      const float* __restrict__ w1, const float* __restrict__ b1,
                      const float* __restrict__ w2, const float* __restrict__ b2,
                      float* __restrict__ out) {
    const int b = blockIdx.x;
    const int t = threadIdx.x;   // 0..127
    __shared__ float ws[2];
    float d[2];
    for (int which = 0; which < 2; ++which) {
        const float* s = (which == 0 ? home_sum : away_sum) + b * 256;
        float acc = b1[t];
        #pragma unroll 4
        for (int k = 0; k < 256; ++k) acc = fmaf(s[k], w1[k * 128 + t], acc);
        acc = fmaxf(acc, 0.f);
        float p = acc * w2[t];
        #pragma unroll
        for (int o = 32; o > 0; o >>= 1) p += __shfl_down(p, o, 64);
        if ((t & 63) == 0) ws[t >> 6] = p;
        __syncthreads();
        d[which] = ws[0] + ws[1] + b2[0];
        __syncthreads();
    }
    if (t == 0) out[b] = 0.5f + 0.5f * tanhf(d[0] - d[1]);
}

// ---------------------------------------------------------------------------
extern "C" void kernel_launch(void* const* d_in, const int* in_sizes, int n_in,
                              void* d_out, int out_size, void* d_ws, size_t ws_size,
                              hipStream_t stream) {
    const float* A         = (const float*)d_in[0];
    const float* X         = (const float*)d_in[1];
    const float* home_mask = (const float*)d_in[2];
    const float* emb1_w    = (const float*)d_in[3];
    const float* emb1_b    = (const float*)d_in[4];
    const float* emb2_w    = (const float*)d_in[5];
    const float* emb2_b    = (const float*)d_in[6];
    const float* rgcn_w[2]    = { (const float*)d_in[7],  (const float*)d_in[14] };
    const float* rgcn_root[2] = { (const float*)d_in[8],  (const float*)d_in[15] };
    const float* rgcn_bias[2] = { (const float*)d_in[9],  (const float*)d_in[16] };
    const float* lina_w[2]    = { (const float*)d_in[10], (const float*)d_in[17] };
    const float* lina_b[2]    = { (const float*)d_in[11], (const float*)d_in[18] };
    const float* linb_w[2]    = { (const float*)d_in[12], (const float*)d_in[19] };
    const float* linb_b[2]    = { (const float*)d_in[13], (const float*)d_in[20] };
    const float* norm_g  = (const float*)d_in[21];
    const float* norm_b  = (const float*)d_in[22];
    const float* phi_w1  = (const float*)d_in[23];
    const float* phi_b1  = (const float*)d_in[24];
    const float* phi_w2  = (const float*)d_in[25];
    const float* phi_b2  = (const float*)d_in[26];
    const float* rho_w1  = (const float*)d_in[27];
    const float* rho_b1  = (const float*)d_in[28];
    const float* rho_w2  = (const float*)d_in[29];
    const float* rho_b2  = (const float*)d_in[30];
    float* out = (float*)d_out;

    // workspace layout (floats)
    float* ws    = (float*)d_ws;
    float* H     = ws;                      // 262144
    float* agg   = ws + 262144;             // 262144
    float* H2    = ws + 524288;             // 262144
    float* mean0 = ws + 786432;             // 262144 (reused as aggraw)
    float* mean1 = ws + 1048576;            // 262144
    float* hsum  = ws + 1310720;            // 2048
    float* asum  = ws + 1312768;            // 2048

    const int NELEM = BNTOT * DV;           // 262144

    k_embed<<<BNTOT, 128, 0, stream>>>(X, emb1_w, emb1_b, emb2_w, emb2_b, H);

    for (int it = 0; it < 2; ++it) {
        if (it == 1) k_add<<<(NELEM + 255) / 256, 256, 0, stream>>>(H, agg, NELEM);
        k_relagg<<<BNTOT, 128, 0, stream>>>(A, H, mean0, mean1);
        k_lin3<<<BNTOT, 128, 0, stream>>>(H, mean0, mean1, rgcn_w[it], rgcn_root[it],
                                          rgcn_bias[it], H2);
        k_absagg<<<BNTOT, 128, 0, stream>>>(A, H2, mean0);  // mean0 = aggraw (reuse)
        k_lnmlp<<<BNTOT, 128, 0, stream>>>(mean0, norm_g, norm_b,
                                           lina_w[it], lina_b[it],
                                           linb_w[it], linb_b[it], agg);
    }
    k_add<<<(NELEM + 255) / 256, 256, 0, stream>>>(H, agg, NELEM);

    k_zero<<<(4096 + 255) / 256, 256, 0, stream>>>(hsum, 4096);
    k_deepset<<<BNTOT, 256, 0, stream>>>(H, home_mask, phi_w1, phi_b1, phi_w2, phi_b2,
                                         hsum, asum);
    k_rho<<<NB, 128, 0, stream>>>(hsum, asum, rho_w1, rho_b1, rho_w2, rho_b2, out);
}

// Round 2
// 351.013 us; speedup vs baseline: 1.1865x; 1.1865x over previous
//
#include <hip/hip_runtime.h>
#include <math.h>

// Shapes (compile-time): B=8, N=256, NID=64, V=GH=128, PHI=256, RHO=128
#define NB    8
#define NN    256
#define BNTOT 2048
#define DV    128
#define DPHI  256

// ---------------------------------------------------------------------------
// Precompute (once per launch, A is constant):
//   M0T[b,j,i] = (A[b,i,j] < 0) ? 1 : 0   (transposed -> relagg reads rows)
//   M1T[b,j,i] = (A[b,i,j] > 0) ? 1 : 0
//   c0f[b*256+j] += count, c1f likewise (atomic partials over i-chunks)
// ---------------------------------------------------------------------------
__global__ __launch_bounds__(256) void k_pre(const float* __restrict__ A,
                      float* __restrict__ M0T, float* __restrict__ M1T,
                      float* __restrict__ c0f, float* __restrict__ c1f) {
    const int b  = blockIdx.x;       // 0..7
    const int i0 = blockIdx.y * 64;  // 4 chunks
    const int t  = threadIdx.x;      // 0..255
    __shared__ float tile[64][65];
    for (int jt = 0; jt < 4; ++jt) {
        const int j0 = jt * 64;
        #pragma unroll
        for (int rep = 0; rep < 16; ++rep) {
            int idx = rep * 256 + t;
            int r = idx >> 6, c = idx & 63;
            tile[r][c] = A[((size_t)(b * 256 + i0 + r)) * 256 + j0 + c];
        }
        __syncthreads();
        #pragma unroll
        for (int rep = 0; rep < 16; ++rep) {
            int idx = rep * 256 + t;
            int jr = idx >> 6, ic = idx & 63;
            float a = tile[ic][jr];
            size_t o = ((size_t)(b * 256 + j0 + jr)) * 256 + i0 + ic;
            M0T[o] = (a < 0.f) ? 1.f : 0.f;
            M1T[o] = (a > 0.f) ? 1.f : 0.f;
        }
        if (t < 64) {
            float c0 = 0.f, c1 = 0.f;
            for (int ic = 0; ic < 64; ++ic) {
                float a = tile[ic][t];
                c0 += (a < 0.f) ? 1.f : 0.f;
                c1 += (a > 0.f) ? 1.f : 0.f;
            }
            atomicAdd(&c0f[b * 256 + j0 + t], c0);
            atomicAdd(&c1f[b * 256 + j0 + t], c1);
        }
        __syncthreads();
    }
}

__global__ __launch_bounds__(256) void k_zero(float* __restrict__ p, int n) {
    const int i = blockIdx.x * blockDim.x + threadIdx.x;
    if (i < n) p[i] = 0.f;
}

// ---------------------------------------------------------------------------
// H = relu(X @ w1 + b1) @ w2 + b2   -- 8 rows/block, 256 threads
// ---------------------------------------------------------------------------
__global__ __launch_bounds__(256) void k_embed(const float* __restrict__ X,
                        const float* __restrict__ w1, const float* __restrict__ b1,
                        const float* __restrict__ w2, const float* __restrict__ b2,
                        float* __restrict__ H) {
    const int r0 = blockIdx.x * 8;
    const int t = threadIdx.x;
    const int f = t & 127, half = t >> 7;
    __shared__ float xs[8][64];
    __shared__ float h1[8][128];
    #pragma unroll
    for (int rep = 0; rep < 2; ++rep) {
        int idx = rep * 256 + t;
        xs[idx >> 6][idx & 63] = X[(size_t)r0 * 64 + idx];
    }
    __syncthreads();
    float acc[4];
    #pragma unroll
    for (int rl = 0; rl < 4; ++rl) acc[rl] = b1[f];
    for (int k = 0; k < 64; ++k) {
        float w = w1[k * 128 + f];
        #pragma unroll
        for (int rl = 0; rl < 4; ++rl) acc[rl] = fmaf(xs[half * 4 + rl][k], w, acc[rl]);
    }
    #pragma unroll
    for (int rl = 0; rl < 4; ++rl) h1[half * 4 + rl][f] = fmaxf(acc[rl], 0.f);
    __syncthreads();
    float acc2[4];
    #pragma unroll
    for (int rl = 0; rl < 4; ++rl) acc2[rl] = b2[f];
    for (int k = 0; k < 128; ++k) {
        float w = w2[k * 128 + f];
        #pragma unroll
        for (int rl = 0; rl < 4; ++rl) acc2[rl] = fmaf(h1[half * 4 + rl][k], w, acc2[rl]);
    }
    #pragma unroll
    for (int rl = 0; rl < 4; ++rl) H[(size_t)(r0 + half * 4 + rl) * 128 + f] = acc2[rl];
}

// ---------------------------------------------------------------------------
// mean_r[b,j,f] = (sum_i M_rT[b,j,i] * H[b,i,f]) / max(c_r,1)
// Block = (jt, b): 8 targets x 128 feats; K-tiled over i (64/tile) via LDS.
// ---------------------------------------------------------------------------
__global__ __launch_bounds__(256) void k_relagg(const float* __restrict__ M0T,
                         const float* __restrict__ M1T,
                         const float* __restrict__ H,
                         const float* __restrict__ c0f, const float* __restrict__ c1f,
                         float* __restrict__ mean0, float* __restrict__ mean1) {
    const int j0 = blockIdx.x * 8;
    const int b  = blockIdx.y;
    const int t = threadIdx.x;
    const int f = t & 127, half = t >> 7;
    const int jg = half * 4;
    __shared__ float ldsH[64 * 128];
    __shared__ float ldsM0[8][64];
    __shared__ float ldsM1[8][64];
    float acc0[4] = {0, 0, 0, 0}, acc1[4] = {0, 0, 0, 0};
    const float* Hb = H + (size_t)b * NN * DV;
    for (int kt = 0; kt < 4; ++kt) {
        const int i0 = kt * 64;
        #pragma unroll
        for (int rep = 0; rep < 32; ++rep)
            ldsH[rep * 256 + t] = Hb[(size_t)i0 * 128 + rep * 256 + t];
        #pragma unroll
        for (int rep = 0; rep < 2; ++rep) {
            int idx = rep * 256 + t;
            int jl = idx >> 6, ii = idx & 63;
            size_t o = ((size_t)(b * 256 + j0 + jl)) * 256 + i0 + ii;
            ldsM0[jl][ii] = M0T[o];
            ldsM1[jl][ii] = M1T[o];
        }
        __syncthreads();
        for (int i = 0; i < 64; ++i) {
            float h = ldsH[i * 128 + f];
            #pragma unroll
            for (int jl = 0; jl < 4; ++jl) {
                acc0[jl] = fmaf(ldsM0[jg + jl][i], h, acc0[jl]);
                acc1[jl] = fmaf(ldsM1[jg + jl][i], h, acc1[jl]);
            }
        }
        __syncthreads();
    }
    #pragma unroll
    for (int jl = 0; jl < 4; ++jl) {
        int row = b * 256 + j0 + jg + jl;
        mean0[(size_t)row * 128 + f] = acc0[jl] / fmaxf(c0f[row], 1.f);
        mean1[(size_t)row * 128 + f] = acc1[jl] / fmaxf(c1f[row], 1.f);
    }
}

// ---------------------------------------------------------------------------
// H2 = H @ Wroot + mean0 @ W0 + mean1 @ W1 + bias   -- 8 rows/block
// ---------------------------------------------------------------------------
__global__ __launch_bounds__(256) void k_lin3(const float* __restrict__ H,
                       const float* __restrict__ mean0, const float* __restrict__ mean1,
                       const float* __restrict__ Wrel, const float* __restrict__ Wroot,
                       const float* __restrict__ bias, float* __restrict__ H2) {
    const int r0 = blockIdx.x * 8;
    const int t = threadIdx.x;
    const int f = t & 127, half = t >> 7;
    __shared__ float hs[8][128], m0s[8][128], m1s[8][128];
    #pragma unroll
    for (int rep = 0; rep < 4; ++rep) {
        int idx = rep * 256 + t;
        int r = idx >> 7, c = idx & 127;
        hs[r][c]  = H[(size_t)(r0 + r) * 128 + c];
        m0s[r][c] = mean0[(size_t)(r0 + r) * 128 + c];
        m1s[r][c] = mean1[(size_t)(r0 + r) * 128 + c];
    }
    __syncthreads();
    const float* W0 = Wrel;
    const float* W1 = Wrel + 128 * 128;
    float acc[4];
    #pragma unroll
    for (int rl = 0; rl < 4; ++rl) acc[rl] = bias[f];
    for (int k = 0; k < 128; ++k) {
        float wr = Wroot[k * 128 + f];
        float w0 = W0[k * 128 + f];
        float w1 = W1[k * 128 + f];
        #pragma unroll
        for (int rl = 0; rl < 4; ++rl) {
            int r = half * 4 + rl;
            acc[rl] = fmaf(hs[r][k], wr, acc[rl]);
            acc[rl] = fmaf(m0s[r][k], w0, acc[rl]);
            acc[rl] = fmaf(m1s[r][k], w1, acc[rl]);
        }
    }
    #pragma unroll
    for (int rl = 0; rl < 4; ++rl)
        H2[(size_t)(r0 + half * 4 + rl) * 128 + f] = acc[rl];
}

// ---------------------------------------------------------------------------
// aggraw[b,i,f] = sum_j |A[b,i,j]| * H2[b,j,f]   -- 8 sources x 128 feats/block
// ---------------------------------------------------------------------------
__global__ __launch_bounds__(256) void k_absagg(const float* __restrict__ A,
                         const float* __restrict__ H2,
                         float* __restrict__ aggraw) {
    const int i0 = blockIdx.x * 8;
    const int b  = blockIdx.y;
    const int t = threadIdx.x;
    const int f = t & 127, half = t >> 7;
    const int ig = half * 4;
    __shared__ float ldsH2[64 * 128];
    __shared__ float ldsA[8][64];
    float acc[4] = {0, 0, 0, 0};
    const float* H2b = H2 + (size_t)b * NN * DV;
    const float* Ab  = A + (size_t)b * NN * NN;
    for (int kt = 0; kt < 4; ++kt) {
        const int j0 = kt * 64;
        #pragma unroll
        for (int rep = 0; rep < 32; ++rep)
            ldsH2[rep * 256 + t] = H2b[(size_t)j0 * 128 + rep * 256 + t];
        #pragma unroll
        for (int rep = 0; rep < 2; ++rep) {
            int idx = rep * 256 + t;
            int il = idx >> 6, jj = idx & 63;
            ldsA[il][jj] = fabsf(Ab[(size_t)(i0 + il) * 256 + j0 + jj]);
        }
        __syncthreads();
        for (int j = 0; j < 64; ++j) {
            float h = ldsH2[j * 128 + f];
            #pragma unroll
            for (int il = 0; il < 4; ++il)
                acc[il] = fmaf(ldsA[ig + il][j], h, acc[il]);
        }
        __syncthreads();
    }
    #pragma unroll
    for (int il = 0; il < 4; ++il)
        aggraw[(size_t)(b * 256 + i0 + ig + il) * 128 + f] = acc[il];
}

// ---------------------------------------------------------------------------
// agg = LN->relu->linA->relu->linB on aggraw; then H += agg  (fused, in-place)
// ---------------------------------------------------------------------------
__global__ __launch_bounds__(256) void k_lnmlp(const float* __restrict__ aggraw,
                        const float* __restrict__ g, const float* __restrict__ bta,
                        const float* __restrict__ law, const float* __restrict__ lab,
                        const float* __restrict__ lbw, const float* __restrict__ lbb,
                        float* __restrict__ H) {
    const int r0 = blockIdx.x * 8;
    const int t = threadIdx.x;
    const int f = t & 127, half = t >> 7;
    __shared__ float xs[8][128];
    __shared__ float us[8][128];
    __shared__ float ms[8], is_[8];
    #pragma unroll
    for (int rep = 0; rep < 4; ++rep) {
        int idx = rep * 256 + t;
        xs[idx >> 7][idx & 127] = aggraw[(size_t)r0 * 128 + idx];
    }
    __syncthreads();
    {
        const int rr = t >> 5, l32 = t & 31;
        float s = 0.f, s2 = 0.f;
        #pragma unroll
        for (int e = 0; e < 4; ++e) {
            float x = xs[rr][l32 + 32 * e];
            s += x; s2 += x * x;
        }
        #pragma unroll
        for (int o = 16; o > 0; o >>= 1) {
            s  += __shfl_down(s, o, 32);
            s2 += __shfl_down(s2, o, 32);
        }
        if (l32 == 0) {
            float m = s * (1.f / 128.f);
            float v = s2 * (1.f / 128.f) - m * m;
            ms[rr] = m;
            is_[rr] = rsqrtf(v + 1e-5f);
        }
    }
    __syncthreads();
    #pragma unroll
    for (int rep = 0; rep < 4; ++rep) {
        int idx = rep * 256 + t;
        int r = idx >> 7, c = idx & 127;
        xs[r][c] = fmaxf((xs[r][c] - ms[r]) * is_[r] * g[c] + bta[c], 0.f);
    }
    __syncthreads();
    float acc[4];
    #pragma unroll
    for (int rl = 0; rl < 4; ++rl) acc[rl] = lab[f];
    for (int k = 0; k < 128; ++k) {
        float w = law[k * 128 + f];
        #pragma unroll
        for (int rl = 0; rl < 4; ++rl)
            acc[rl] = fmaf(xs[half * 4 + rl][k], w, acc[rl]);
    }
    #pragma unroll
    for (int rl = 0; rl < 4; ++rl) us[half * 4 + rl][f] = fmaxf(acc[rl], 0.f);
    __syncthreads();
    float acc2[4];
    #pragma unroll
    for (int rl = 0; rl < 4; ++rl) acc2[rl] = lbb[f];
    for (int k = 0; k < 128; ++k) {
        float w = lbw[k * 128 + f];
        #pragma unroll
        for (int rl = 0; rl < 4; ++rl)
            acc2[rl] = fmaf(us[half * 4 + rl][k], w, acc2[rl]);
    }
    #pragma unroll
    for (int rl = 0; rl < 4; ++rl) {
        size_t o = (size_t)(r0 + half * 4 + rl) * 128 + f;
        H[o] = H[o] + acc2[rl];
    }
}

// ---------------------------------------------------------------------------
// DeepSet phi (2 layers) + masked pooling with per-block partials + atomics
// ---------------------------------------------------------------------------
__global__ __launch_bounds__(256) void k_deepset(const float* __restrict__ H,
                          const float* __restrict__ hm,
                          const float* __restrict__ w1, const float* __restrict__ b1,
                          const float* __restrict__ w2, const float* __restrict__ b2,
                          float* __restrict__ hsum, float* __restrict__ asum) {
    const int r0 = blockIdx.x * 8;
    const int b = r0 >> 8;
    const int t = threadIdx.x;   // = output feature f (0..255)
    __shared__ float hs[8][128];
    __shared__ float ph[8][256];
    __shared__ float hmv[8];
    #pragma unroll
    for (int rep = 0; rep < 4; ++rep) {
        int idx = rep * 256 + t;
        hs[idx >> 7][idx & 127] = H[(size_t)r0 * 128 + idx];
    }
    if (t < 8) hmv[t] = hm[r0 + t];
    __syncthreads();
    float acc[8];
    #pragma unroll
    for (int rl = 0; rl < 8; ++rl) acc[rl] = b1[t];
    for (int k = 0; k < 128; ++k) {
        float w = w1[k * 256 + t];
        #pragma unroll
        for (int rl = 0; rl < 8; ++rl)
            acc[rl] = fmaf(hs[rl][k], w, acc[rl]);
    }
    #pragma unroll
    for (int rl = 0; rl < 8; ++rl) ph[rl][t] = fmaxf(acc[rl], 0.f);
    __syncthreads();
    float acc2[8];
    #pragma unroll
    for (int rl = 0; rl < 8; ++rl) acc2[rl] = b2[t];
    for (int k = 0; k < 256; ++k) {
        float w = w2[k * 256 + t];
        #pragma unroll
        for (int rl = 0; rl < 8; ++rl)
            acc2[rl] = fmaf(ph[rl][k], w, acc2[rl]);
    }
    float hpart = 0.f, apart = 0.f;
    #pragma unroll
    for (int rl = 0; rl < 8; ++rl) {
        float p = fmaxf(acc2[rl], 0.f);
        hpart = fmaf(p, hmv[rl], hpart);
        apart = fmaf(p, 1.f - hmv[rl], apart);
    }
    atomicAdd(&hsum[b * 256 + t], hpart);
    atomicAdd(&asum[b * 256 + t], apart);
}

// ---------------------------------------------------------------------------
// out[b] = 0.5 + 0.5*tanh(rho(home)-rho(away))
// ---------------------------------------------------------------------------
__global__ __launch_bounds__(128) void k_rho(const float* __restrict__ home_sum,
                      const float* __restrict__ away_sum,
                      const float* __restrict__ w1, const float* __restrict__ b1,
                      const float* __restrict__ w2, const float* __restrict__ b2,
                      float* __restrict__ out) {
    const int b = blockIdx.x;
    const int t = threadIdx.x;   // 0..127
    __shared__ float ws[2];
    float d[2];
    for (int which = 0; which < 2; ++which) {
        const float* s = (which == 0 ? home_sum : away_sum) + b * 256;
        float acc = b1[t];
        #pragma unroll 4
        for (int k = 0; k < 256; ++k) acc = fmaf(s[k], w1[k * 128 + t], acc);
        acc = fmaxf(acc, 0.f);
        float p = acc * w2[t];
        #pragma unroll
        for (int o = 32; o > 0; o >>= 1) p += __shfl_down(p, o, 64);
        if ((t & 63) == 0) ws[t >> 6] = p;
        __syncthreads();
        d[which] = ws[0] + ws[1] + b2[0];
        __syncthreads();
    }
    if (t == 0) out[b] = 0.5f + 0.5f * tanhf(d[0] - d[1]);
}

// ---------------------------------------------------------------------------
extern "C" void kernel_launch(void* const* d_in, const int* in_sizes, int n_in,
                              void* d_out, int out_size, void* d_ws, size_t ws_size,
                              hipStream_t stream) {
    const float* A         = (const float*)d_in[0];
    const float* X         = (const float*)d_in[1];
    const float* home_mask = (const float*)d_in[2];
    const float* emb1_w    = (const float*)d_in[3];
    const float* emb1_b    = (const float*)d_in[4];
    const float* emb2_w    = (const float*)d_in[5];
    const float* emb2_b    = (const float*)d_in[6];
    const float* rgcn_w[2]    = { (const float*)d_in[7],  (const float*)d_in[14] };
    const float* rgcn_root[2] = { (const float*)d_in[8],  (const float*)d_in[15] };
    const float* rgcn_bias[2] = { (const float*)d_in[9],  (const float*)d_in[16] };
    const float* lina_w[2]    = { (const float*)d_in[10], (const float*)d_in[17] };
    const float* lina_b[2]    = { (const float*)d_in[11], (const float*)d_in[18] };
    const float* linb_w[2]    = { (const float*)d_in[12], (const float*)d_in[19] };
    const float* linb_b[2]    = { (const float*)d_in[13], (const float*)d_in[20] };
    const float* norm_g  = (const float*)d_in[21];
    const float* norm_b  = (const float*)d_in[22];
    const float* phi_w1  = (const float*)d_in[23];
    const float* phi_b1  = (const float*)d_in[24];
    const float* phi_w2  = (const float*)d_in[25];
    const float* phi_b2  = (const float*)d_in[26];
    const float* rho_w1  = (const float*)d_in[27];
    const float* rho_b1  = (const float*)d_in[28];
    const float* rho_w2  = (const float*)d_in[29];
    const float* rho_b2  = (const float*)d_in[30];
    float* out = (float*)d_out;

    // workspace layout (floats): total 2,105,344 floats = 8.42 MB
    float* ws    = (float*)d_ws;
    float* H     = ws;                       // 262144
    float* H2    = ws + 262144;              // 262144
    float* mean0 = ws + 524288;              // 262144 (reused as aggraw)
    float* mean1 = ws + 786432;              // 262144
    float* M0T   = ws + 1048576;             // 524288
    float* M1T   = ws + 1572864;             // 524288
    float* c0f   = ws + 2097152;             // 2048
    float* c1f   = ws + 2099200;             // 2048
    float* hsum  = ws + 2101248;             // 2048
    float* asum  = ws + 2103296;             // 2048

    // zero c0f,c1f,hsum,asum (contiguous 8192 floats)
    k_zero<<<32, 256, 0, stream>>>(c0f, 8192);
    k_pre<<<dim3(8, 4), 256, 0, stream>>>(A, M0T, M1T, c0f, c1f);
    k_embed<<<256, 256, 0, stream>>>(X, emb1_w, emb1_b, emb2_w, emb2_b, H);

    for (int it = 0; it < 2; ++it) {
        k_relagg<<<dim3(32, 8), 256, 0, stream>>>(M0T, M1T, H, c0f, c1f, mean0, mean1);
        k_lin3<<<256, 256, 0, stream>>>(H, mean0, mean1, rgcn_w[it], rgcn_root[it],
                                        rgcn_bias[it], H2);
        k_absagg<<<dim3(32, 8), 256, 0, stream>>>(A, H2, mean0);  // mean0 = aggraw
        k_lnmlp<<<256, 256, 0, stream>>>(mean0, norm_g, norm_b,
                                         lina_w[it], lina_b[it],
                                         linb_w[it], linb_b[it], H);  // H += agg fused
    }

    k_deepset<<<256, 256, 0, stream>>>(H, home_mask, phi_w1, phi_b1, phi_w2, phi_b2,
                                       hsum, asum);
    k_rho<<<NB, 128, 0, stream>>>(hsum, asum, rho_w1, rho_b1, rho_w2, rho_b2, out);
}

// Round 3
// 253.884 us; speedup vs baseline: 1.6405x; 1.3826x over previous
//
#include <hip/hip_runtime.h>
#include <math.h>

// Shapes: B=8, N=256, NID=64, V=GH=128, PHI=256, RHO=128
#define NB    8
#define NN    256
#define BNTOT 2048
#define DV    128

// ---------------------------------------------------------------------------
// k_pre: M0T[b,j,i] = (A[b,i,j]<0), M1T = (A[b,i,j]>0); counts via atomics.
// Grid 128 blocks: (b, i-chunk, j-chunk) of 64x64 tiles.
// ---------------------------------------------------------------------------
__global__ __launch_bounds__(256) void k_pre(const float* __restrict__ A,
        float* __restrict__ M0T, float* __restrict__ M1T,
        float* __restrict__ c0f, float* __restrict__ c1f) {
    const int b  = blockIdx.x >> 4;
    const int i0 = ((blockIdx.x >> 2) & 3) * 64;
    const int j0 = (blockIdx.x & 3) * 64;
    const int t  = threadIdx.x;
    __shared__ float tile[64][65];
    #pragma unroll
    for (int rep = 0; rep < 16; ++rep) {
        int idx = rep * 256 + t;
        int r = idx >> 6, c = idx & 63;
        tile[r][c] = A[((size_t)(b * 256 + i0 + r)) * 256 + j0 + c];
    }
    __syncthreads();
    #pragma unroll
    for (int rep = 0; rep < 16; ++rep) {
        int idx = rep * 256 + t;
        int jr = idx >> 6, ic = idx & 63;
        float a = tile[ic][jr];
        size_t o = ((size_t)(b * 256 + j0 + jr)) * 256 + i0 + ic;
        M0T[o] = (a < 0.f) ? 1.f : 0.f;
        M1T[o] = (a > 0.f) ? 1.f : 0.f;
    }
    if (t < 64) {
        float c0 = 0.f, c1 = 0.f;
        for (int ic = 0; ic < 64; ++ic) {
            float a = tile[ic][t];
            c0 += (a < 0.f) ? 1.f : 0.f;
            c1 += (a > 0.f) ? 1.f : 0.f;
        }
        atomicAdd(&c0f[b * 256 + j0 + t], c0);
        atomicAdd(&c1f[b * 256 + j0 + t], c1);
    }
}

__global__ __launch_bounds__(256) void k_zero(float* __restrict__ p, int n) {
    const int i = blockIdx.x * blockDim.x + threadIdx.x;
    if (i < n) p[i] = 0.f;
}

// ---------------------------------------------------------------------------
// k_embed: H = relu(X@w1+b1)@w2+b2.  4 rows/block, grid 512, 256 thr.
// Thread: f = t&127, half rh = t>>7 owns rows rh*2+{0,1}.
// ---------------------------------------------------------------------------
__global__ __launch_bounds__(256, 2) void k_embed(const float* __restrict__ X,
        const float* __restrict__ w1, const float* __restrict__ b1,
        const float* __restrict__ w2, const float* __restrict__ b2,
        float* __restrict__ H) {
    const int r0 = blockIdx.x * 4;
    const int t = threadIdx.x;
    const int f = t & 127, rh = t >> 7;
    __shared__ __align__(16) float xsp[64 * 4];    // [k][r]
    __shared__ __align__(16) float h1p[128 * 4];   // [k][r]
    {
        int k = t & 63, r = t >> 6;
        xsp[k * 4 + r] = X[(size_t)(r0 + r) * 64 + k];
    }
    __syncthreads();
    float a1[2] = {b1[f], b1[f]};
    #pragma unroll 8
    for (int k = 0; k < 64; ++k) {
        float w = w1[k * 128 + f];
        float2 xv = *(const float2*)&xsp[k * 4 + rh * 2];
        a1[0] = fmaf(xv.x, w, a1[0]);
        a1[1] = fmaf(xv.y, w, a1[1]);
    }
    h1p[f * 4 + rh * 2 + 0] = fmaxf(a1[0], 0.f);
    h1p[f * 4 + rh * 2 + 1] = fmaxf(a1[1], 0.f);
    __syncthreads();
    float a2[2] = {b2[f], b2[f]};
    #pragma unroll 8
    for (int k = 0; k < 128; ++k) {
        float w = w2[k * 128 + f];
        float2 hv = *(const float2*)&h1p[k * 4 + rh * 2];
        a2[0] = fmaf(hv.x, w, a2[0]);
        a2[1] = fmaf(hv.y, w, a2[1]);
    }
    H[(size_t)(r0 + rh * 2 + 0) * 128 + f] = a2[0];
    H[(size_t)(r0 + rh * 2 + 1) * 128 + f] = a2[1];
}

// ---------------------------------------------------------------------------
// k_gcn1 = relagg + lin3 fused.  4 targets j per block, grid (64 j-chunks x 8 b).
// Phase A: mean_r[j,f] = sum_i M_rT[j,i]*H[i,f] / max(c_r,1)  (K=256 via LDS)
// Phase B: H2[j,f] = H[j,:]@Wroot + m0@W0 + m1@W1 + bias
// ---------------------------------------------------------------------------
__global__ __launch_bounds__(256, 2) void k_gcn1(
        const float* __restrict__ M0T, const float* __restrict__ M1T,
        const float* __restrict__ H,
        const float* __restrict__ c0f, const float* __restrict__ c1f,
        const float* __restrict__ Wrel, const float* __restrict__ Wroot,
        const float* __restrict__ bias, float* __restrict__ H2) {
    const int b  = blockIdx.x >> 6;
    const int j0 = (blockIdx.x & 63) * 4;
    const int t  = threadIdx.x;
    const int f  = t & 127;
    const int rh = t >> 7;
    __shared__ __align__(16) float ldsH[64 * 128];   // 32 KB
    __shared__ __align__(16) float ldsMM[64 * 8];    // [i][rh*4 + rel*2 + rl]
    __shared__ __align__(16) float pb[128 * 16];     // [k][rh*8 + slot] 8 KB
    float acc0[2] = {0.f, 0.f}, acc1[2] = {0.f, 0.f};
    const float* Hb = H + (size_t)b * NN * DV;

    for (int kt = 0; kt < 4; ++kt) {
        const int i0 = kt * 64;
        {
            const float4* src = (const float4*)(Hb + i0 * 128);
            float4* dst = (float4*)ldsH;
            #pragma unroll
            for (int rep = 0; rep < 8; ++rep)
                dst[rep * 256 + t] = src[rep * 256 + t];
        }
        #pragma unroll
        for (int s = 0; s < 2; ++s) {
            int idx = s * 256 + t;          // [0,512)
            int i   = idx & 63;
            int rem = idx >> 6;             // rel*4 + r
            int rel = rem >> 2;
            int r   = rem & 3;
            const float* Msrc = rel ? M1T : M0T;
            float v = Msrc[((size_t)(b * 256 + j0 + r)) * 256 + i0 + i];
            ldsMM[i * 8 + (r >> 1) * 4 + rel * 2 + (r & 1)] = v;
        }
        __syncthreads();
        #pragma unroll 8
        for (int i = 0; i < 64; ++i) {
            float h = ldsH[i * 128 + f];
            float4 mm = *(const float4*)&ldsMM[i * 8 + rh * 4];
            acc0[0] = fmaf(mm.x, h, acc0[0]);
            acc0[1] = fmaf(mm.y, h, acc0[1]);
            acc1[0] = fmaf(mm.z, h, acc1[0]);
            acc1[1] = fmaf(mm.w, h, acc1[1]);
        }
        __syncthreads();
    }
    // Epilogue A: divide by counts; pack phase-B row operands into pb.
    #pragma unroll
    for (int rl = 0; rl < 2; ++rl) {
        int row = b * 256 + j0 + rh * 2 + rl;
        pb[f * 16 + rh * 8 + 4 + rl] = acc0[rl] / fmaxf(c0f[row], 1.f);
        pb[f * 16 + rh * 8 + 6 + rl] = acc1[rl] / fmaxf(c1f[row], 1.f);
    }
    #pragma unroll
    for (int s = 0; s < 2; ++s) {
        int idx = s * 256 + t;  // [0,512): 4 rows x 128 k
        int r = idx >> 7, k = idx & 127;
        pb[k * 16 + (r >> 1) * 8 + (r & 1)] =
            H[((size_t)(b * 256 + j0 + r)) * 128 + k];
    }
    __syncthreads();
    const float* W0 = Wrel;
    const float* W1 = Wrel + 128 * 128;
    float acc[2] = {bias[f], bias[f]};
    #pragma unroll 8
    for (int k = 0; k < 128; ++k) {
        float wr = Wroot[k * 128 + f];
        float w0 = W0[k * 128 + f];
        float w1 = W1[k * 128 + f];
        const float* pbk = &pb[k * 16 + rh * 8];
        float2 hv = *(const float2*)pbk;
        float4 mv = *(const float4*)(pbk + 4);
        acc[0] = fmaf(hv.x, wr, acc[0]);
        acc[1] = fmaf(hv.y, wr, acc[1]);
        acc[0] = fmaf(mv.x, w0, acc[0]);
        acc[1] = fmaf(mv.y, w0, acc[1]);
        acc[0] = fmaf(mv.z, w1, acc[0]);
        acc[1] = fmaf(mv.w, w1, acc[1]);
    }
    H2[((size_t)(b * 256 + j0 + rh * 2 + 0)) * 128 + f] = acc[0];
    H2[((size_t)(b * 256 + j0 + rh * 2 + 1)) * 128 + f] = acc[1];
}

// ---------------------------------------------------------------------------
// k_gcn2 = absagg + LN + MLP + H-update fused.  4 source rows i per block.
// ---------------------------------------------------------------------------
__global__ __launch_bounds__(256, 2) void k_gcn2(
        const float* __restrict__ A, const float* __restrict__ H2,
        const float* __restrict__ g, const float* __restrict__ bta,
        const float* __restrict__ law, const float* __restrict__ lab,
        const float* __restrict__ lbw, const float* __restrict__ lbb,
        float* __restrict__ H) {
    const int b  = blockIdx.x >> 6;
    const int i0 = (blockIdx.x & 63) * 4;
    const int t  = threadIdx.x;
    const int f  = t & 127;
    const int rh = t >> 7;
    const int wv = (t >> 6) & 1;
    __shared__ __align__(16) float ldsH2[64 * 128];  // 32 KB
    __shared__ __align__(16) float ldsAA[64 * 4];    // [j][r]
    __shared__ __align__(16) float xsp[128 * 4];     // [k][r]
    __shared__ __align__(16) float usp[128 * 4];
    __shared__ float red[4][2][2];
    __shared__ float mi[4][2];
    float acc[2] = {0.f, 0.f};
    const float* H2b = H2 + (size_t)b * NN * DV;
    const float* Ab  = A + (size_t)b * NN * NN;
    for (int kt = 0; kt < 4; ++kt) {
        const int j0 = kt * 64;
        {
            const float4* src = (const float4*)(H2b + j0 * 128);
            float4* dst = (float4*)ldsH2;
            #pragma unroll
            for (int rep = 0; rep < 8; ++rep)
                dst[rep * 256 + t] = src[rep * 256 + t];
        }
        {
            int j = t & 63, r = t >> 6;
            ldsAA[j * 4 + (r >> 1) * 2 + (r & 1)] =
                fabsf(Ab[((size_t)(i0 + r)) * 256 + j0 + j]);
        }
        __syncthreads();
        #pragma unroll 8
        for (int j = 0; j < 64; ++j) {
            float h = ldsH2[j * 128 + f];
            float2 aa = *(const float2*)&ldsAA[j * 4 + rh * 2];
            acc[0] = fmaf(aa.x, h, acc[0]);
            acc[1] = fmaf(aa.y, h, acc[1]);
        }
        __syncthreads();
    }
    // LayerNorm stats per row (f-dim spread over 2 waves of the half)
    #pragma unroll
    for (int rl = 0; rl < 2; ++rl) {
        float s = acc[rl], s2 = acc[rl] * acc[rl];
        #pragma unroll
        for (int o = 32; o > 0; o >>= 1) {
            s  += __shfl_down(s, o, 64);
            s2 += __shfl_down(s2, o, 64);
        }
        if ((t & 63) == 0) {
            red[rh * 2 + rl][wv][0] = s;
            red[rh * 2 + rl][wv][1] = s2;
        }
    }
    __syncthreads();
    if (t < 4) {
        float s  = red[t][0][0] + red[t][1][0];
        float s2 = red[t][0][1] + red[t][1][1];
        float m = s * (1.f / 128.f);
        float v = s2 * (1.f / 128.f) - m * m;
        mi[t][0] = m;
        mi[t][1] = rsqrtf(v + 1e-5f);
    }
    __syncthreads();
    #pragma unroll
    for (int rl = 0; rl < 2; ++rl) {
        int r = rh * 2 + rl;
        xsp[f * 4 + r] = fmaxf((acc[rl] - mi[r][0]) * mi[r][1] * g[f] + bta[f], 0.f);
    }
    __syncthreads();
    float a1[2] = {lab[f], lab[f]};
    #pragma unroll 8
    for (int k = 0; k < 128; ++k) {
        float w = law[k * 128 + f];
        float2 xv = *(const float2*)&xsp[k * 4 + rh * 2];
        a1[0] = fmaf(xv.x, w, a1[0]);
        a1[1] = fmaf(xv.y, w, a1[1]);
    }
    usp[f * 4 + rh * 2 + 0] = fmaxf(a1[0], 0.f);
    usp[f * 4 + rh * 2 + 1] = fmaxf(a1[1], 0.f);
    __syncthreads();
    float a2[2] = {lbb[f], lbb[f]};
    #pragma unroll 8
    for (int k = 0; k < 128; ++k) {
        float w = lbw[k * 128 + f];
        float2 uv = *(const float2*)&usp[k * 4 + rh * 2];
        a2[0] = fmaf(uv.x, w, a2[0]);
        a2[1] = fmaf(uv.y, w, a2[1]);
    }
    #pragma unroll
    for (int rl = 0; rl < 2; ++rl) {
        size_t o = ((size_t)(b * 256 + i0 + rh * 2 + rl)) * 128 + f;
        H[o] = H[o] + a2[rl];
    }
}

// ---------------------------------------------------------------------------
// k_deepset: phi (2 layers, float4 weights) + masked pool, 4 rows/block.
// Wave g owns row g; thread covers feature quad 4*(t&63).
// ---------------------------------------------------------------------------
__global__ __launch_bounds__(256, 2) void k_deepset(
        const float* __restrict__ H, const float* __restrict__ hm,
        const float* __restrict__ w1, const float* __restrict__ b1,
        const float* __restrict__ w2, const float* __restrict__ b2,
        float* __restrict__ hsum, float* __restrict__ asum) {
    const int r0 = blockIdx.x * 4;
    const int b  = r0 >> 8;
    const int t  = threadIdx.x;
    const int g  = t >> 6;
    const int f4 = (t & 63) * 4;
    __shared__ __align__(16) float hs[4][128];
    __shared__ __align__(16) float ph[4][256];
    __shared__ __align__(16) float pool[4][512];
    __shared__ float hmv[4];
    #pragma unroll
    for (int s = 0; s < 2; ++s) {
        int idx = s * 256 + t;
        hs[idx >> 7][idx & 127] = H[(size_t)(r0 + (idx >> 7)) * 128 + (idx & 127)];
    }
    if (t < 4) hmv[t] = hm[r0 + t];
    __syncthreads();
    float4 a1 = *(const float4*)&b1[f4];
    #pragma unroll 8
    for (int k = 0; k < 128; ++k) {
        float4 wv = *(const float4*)&w1[k * 256 + f4];
        float hk = hs[g][k];
        a1.x = fmaf(wv.x, hk, a1.x);
        a1.y = fmaf(wv.y, hk, a1.y);
        a1.z = fmaf(wv.z, hk, a1.z);
        a1.w = fmaf(wv.w, hk, a1.w);
    }
    float4 pr;
    pr.x = fmaxf(a1.x, 0.f); pr.y = fmaxf(a1.y, 0.f);
    pr.z = fmaxf(a1.z, 0.f); pr.w = fmaxf(a1.w, 0.f);
    *(float4*)&ph[g][f4] = pr;
    __syncthreads();
    float4 a2 = *(const float4*)&b2[f4];
    #pragma unroll 8
    for (int k = 0; k < 256; ++k) {
        float4 wv = *(const float4*)&w2[k * 256 + f4];
        float pk = ph[g][k];
        a2.x = fmaf(wv.x, pk, a2.x);
        a2.y = fmaf(wv.y, pk, a2.y);
        a2.z = fmaf(wv.z, pk, a2.z);
        a2.w = fmaf(wv.w, pk, a2.w);
    }
    float m = hmv[g];
    float4 p;
    p.x = fmaxf(a2.x, 0.f); p.y = fmaxf(a2.y, 0.f);
    p.z = fmaxf(a2.z, 0.f); p.w = fmaxf(a2.w, 0.f);
    float4 hq = make_float4(p.x * m, p.y * m, p.z * m, p.w * m);
    float4 aq = make_float4(p.x - hq.x, p.y - hq.y, p.z - hq.z, p.w - hq.w);
    *(float4*)&pool[g][f4]       = hq;
    *(float4*)&pool[g][256 + f4] = aq;
    __syncthreads();
    // block-reduce 4 rows, then one atomic per feature per array
    {
        float hp = pool[0][t] + pool[1][t] + pool[2][t] + pool[3][t];
        float ap = pool[0][256 + t] + pool[1][256 + t] + pool[2][256 + t] + pool[3][256 + t];
        atomicAdd(&hsum[b * 256 + t], hp);
        atomicAdd(&asum[b * 256 + t], ap);
    }
}

// ---------------------------------------------------------------------------
// k_rho: out[b] = 0.5 + 0.5*tanh(rho(home)-rho(away))
// ---------------------------------------------------------------------------
__global__ __launch_bounds__(128) void k_rho(const float* __restrict__ home_sum,
        const float* __restrict__ away_sum,
        const float* __restrict__ w1, const float* __restrict__ b1,
        const float* __restrict__ w2, const float* __restrict__ b2,
        float* __restrict__ out) {
    const int b = blockIdx.x;
    const int t = threadIdx.x;
    __shared__ float ws[2];
    float d[2];
    for (int which = 0; which < 2; ++which) {
        const float* s = (which == 0 ? home_sum : away_sum) + b * 256;
        float acc = b1[t];
        #pragma unroll 8
        for (int k = 0; k < 256; ++k) acc = fmaf(s[k], w1[k * 128 + t], acc);
        acc = fmaxf(acc, 0.f);
        float p = acc * w2[t];
        #pragma unroll
        for (int o = 32; o > 0; o >>= 1) p += __shfl_down(p, o, 64);
        if ((t & 63) == 0) ws[t >> 6] = p;
        __syncthreads();
        d[which] = ws[0] + ws[1] + b2[0];
        __syncthreads();
    }
    if (t == 0) out[b] = 0.5f + 0.5f * tanhf(d[0] - d[1]);
}

// ---------------------------------------------------------------------------
extern "C" void kernel_launch(void* const* d_in, const int* in_sizes, int n_in,
                              void* d_out, int out_size, void* d_ws, size_t ws_size,
                              hipStream_t stream) {
    const float* A         = (const float*)d_in[0];
    const float* X         = (const float*)d_in[1];
    const float* home_mask = (const float*)d_in[2];
    const float* emb1_w    = (const float*)d_in[3];
    const float* emb1_b    = (const float*)d_in[4];
    const float* emb2_w    = (const float*)d_in[5];
    const float* emb2_b    = (const float*)d_in[6];
    const float* rgcn_w[2]    = { (const float*)d_in[7],  (const float*)d_in[14] };
    const float* rgcn_root[2] = { (const float*)d_in[8],  (const float*)d_in[15] };
    const float* rgcn_bias[2] = { (const float*)d_in[9],  (const float*)d_in[16] };
    const float* lina_w[2]    = { (const float*)d_in[10], (const float*)d_in[17] };
    const float* lina_b[2]    = { (const float*)d_in[11], (const float*)d_in[18] };
    const float* linb_w[2]    = { (const float*)d_in[12], (const float*)d_in[19] };
    const float* linb_b[2]    = { (const float*)d_in[13], (const float*)d_in[20] };
    const float* norm_g  = (const float*)d_in[21];
    const float* norm_b  = (const float*)d_in[22];
    const float* phi_w1  = (const float*)d_in[23];
    const float* phi_b1  = (const float*)d_in[24];
    const float* phi_w2  = (const float*)d_in[25];
    const float* phi_b2  = (const float*)d_in[26];
    const float* rho_w1  = (const float*)d_in[27];
    const float* rho_b1  = (const float*)d_in[28];
    const float* rho_w2  = (const float*)d_in[29];
    const float* rho_b2  = (const float*)d_in[30];
    float* out = (float*)d_out;

    float* ws   = (float*)d_ws;
    float* H    = ws;                  // 262144
    float* H2   = ws + 262144;         // 262144
    float* M0T  = ws + 524288;         // 524288
    float* M1T  = ws + 1048576;        // 524288
    float* c0f  = ws + 1572864;        // 2048
    float* c1f  = ws + 1574912;        // 2048
    float* hsum = ws + 1576960;        // 2048
    float* asum = ws + 1579008;        // 2048

    k_zero<<<32, 256, 0, stream>>>(c0f, 8192);
    k_pre<<<128, 256, 0, stream>>>(A, M0T, M1T, c0f, c1f);
    k_embed<<<512, 256, 0, stream>>>(X, emb1_w, emb1_b, emb2_w, emb2_b, H);

    for (int it = 0; it < 2; ++it) {
        k_gcn1<<<512, 256, 0, stream>>>(M0T, M1T, H, c0f, c1f,
                                        rgcn_w[it], rgcn_root[it], rgcn_bias[it], H2);
        k_gcn2<<<512, 256, 0, stream>>>(A, H2, norm_g, norm_b,
                                        lina_w[it], lina_b[it],
                                        linb_w[it], linb_b[it], H);
    }

    k_deepset<<<512, 256, 0, stream>>>(H, home_mask, phi_w1, phi_b1, phi_w2, phi_b2,
                                       hsum, asum);
    k_rho<<<NB, 128, 0, stream>>>(hsum, asum, rho_w1, rho_b1, rho_w2, rho_b2, out);
}